// Round 1
// baseline (1362.532 us; speedup 1.0000x reference)
//
#include <hip/hip_runtime.h>
#include <math.h>

// Problem constants: B=8, C=64, H=W=64, N=4096, N4=1024.
// Layouts: all feature maps kept as (B, 64, N) with N contiguous (matches input x).

// ---------------------------------------------------------------------------
// 2x2 average pool: x (B,64,64,64) -> xp (B,64,32,32). Pool commutes with the
// 1x1 conv, so stage-1 pooled queries are computed as conv(pool(x)).
// ---------------------------------------------------------------------------
__global__ __launch_bounds__(256) void pool_kernel(const float* __restrict__ x,
                                                   float* __restrict__ xp) {
    int idx = blockIdx.x * 256 + threadIdx.x;   // over B*64*1024 = 524288
    int m  = idx & 1023;                        // pooled position hp*32+wp
    int hp = m >> 5, wp = m & 31;
    int bc = idx >> 10;                         // b*64 + c
    const float* xb = x + bc * 4096 + hp * 128 + wp * 2;
    xp[idx] = 0.25f * (xb[0] + xb[1] + xb[64] + xb[65]);
}

// ---------------------------------------------------------------------------
// 1x1 conv = per-batch 64x64 matmul. Thread owns one column n: x-column in
// VGPRs, weights are wave-uniform -> scalar loads (s_load_dwordx16), so each
// FMA is a single v_fmac with SGPR operand.
// ---------------------------------------------------------------------------
template<int NMAT>
__global__ __launch_bounds__(128) void proj_kernel(
    const float* __restrict__ X, int N,
    const float* __restrict__ W0, const float* __restrict__ Bs0, float* __restrict__ Y0,
    const float* __restrict__ W1, const float* __restrict__ Bs1, float* __restrict__ Y1,
    const float* __restrict__ W2, const float* __restrict__ Bs2, float* __restrict__ Y2)
{
    int n = blockIdx.x * 128 + threadIdx.x;
    int b = blockIdx.y;
    float xv[64];
    #pragma unroll
    for (int c = 0; c < 64; ++c) xv[c] = X[(b * 64 + c) * N + n];

    #pragma unroll
    for (int mat = 0; mat < NMAT; ++mat) {
        const float* W  = (mat == 0) ? W0  : (mat == 1) ? W1  : W2;
        const float* Bs = (mat == 0) ? Bs0 : (mat == 1) ? Bs1 : Bs2;
        float*       Y  = (mat == 0) ? Y0  : (mat == 1) ? Y1  : Y2;
        for (int o = 0; o < 64; ++o) {
            float acc = Bs[o];
            #pragma unroll
            for (int c = 0; c < 64; ++c) acc += W[o * 64 + c] * xv[c];
            Y[(b * 64 + o) * N + n] = acc;
        }
    }
}

// ---------------------------------------------------------------------------
// Flash attention over (B,64,*) operands.
//   Q: (B,64,NQ) columns are query rows.  K,V: (B,64,L).
//   Block: 256 threads = 4 waves. Thread owns query row r = t&63 and, per
//   wave g: j-block [16g,16g+16) for scores, c-block [16g,16g+16) for output.
//   K/V elements are wave-uniform (g via readfirstlane) -> scalar loads.
//   LDS used only for the P-tile (64x68 padded) and row max/sum reductions.
//   NSPLIT>1: grid.z splits the KV range; writes unnormalized partials + m,l.
//   NSPLIT==1: writes final output, optionally gamma*O/l + resid.
// ---------------------------------------------------------------------------
template<int NSPLIT>
__global__ __launch_bounds__(256) void flash_kernel(
    const float* __restrict__ Qm, const float* __restrict__ Km,
    const float* __restrict__ Vm, int NQ, int L,
    float* __restrict__ Ofinal, const float* __restrict__ resid,
    const float* __restrict__ gamma_p,
    float* __restrict__ Opart,   // (B, NSPLIT, 64, NQ)
    float* __restrict__ Mbuf,    // (B, NSPLIT, NQ)
    float* __restrict__ Lbuf)    // (B, NSPLIT, NQ)
{
    const int t   = threadIdx.x;
    const int r   = t & 63;
    const int g_u = __builtin_amdgcn_readfirstlane(t >> 6);  // wave id, forced uniform
    const int jb  = g_u * 16;
    const int cb  = g_u * 16;
    const int b   = blockIdx.y;
    const int m0  = blockIdx.x * 64;
    const int s   = (NSPLIT > 1) ? blockIdx.z : 0;
    const int SL  = L / NSPLIT;
    const int k_begin = s * SL;
    const int k_end   = k_begin + SL;

    __shared__ __align__(16) float Ss[64 * 68];   // P tile, padded stride 68
    __shared__ float red[2 * 256];                // [0..255]=max slots, [256..511]=sum slots

    // Query row r into registers (coalesced: lanes read consecutive columns).
    float q[64];
    #pragma unroll
    for (int c = 0; c < 64; ++c) q[c] = Qm[(b * 64 + c) * NQ + m0 + r];

    float O[16];
    #pragma unroll
    for (int i = 0; i < 16; ++i) O[i] = 0.f;
    float m_run = -__builtin_inff();
    float l_run = 0.f;

    const float* Kb = Km + b * 64 * L;
    const float* Vb = Vm + b * 64 * L;

    for (int kt = k_begin; kt < k_end; kt += 64) {
        // ----- S = q . K for this wave's 16 j columns (K via scalar loads) -----
        float sv[16];
        #pragma unroll
        for (int jj = 0; jj < 16; ++jj) sv[jj] = 0.f;
        #pragma unroll
        for (int c = 0; c < 64; ++c) {
            const float* kr = Kb + c * L + kt + jb;   // 16 consecutive, wave-uniform
            #pragma unroll
            for (int jj = 0; jj < 16; ++jj) sv[jj] += q[c] * kr[jj];
        }
        float lm = sv[0];
        #pragma unroll
        for (int jj = 1; jj < 16; ++jj) lm = fmaxf(lm, sv[jj]);

        // ----- row max across the 4 waves -----
        red[t] = lm;
        __syncthreads();
        float tm = fmaxf(fmaxf(red[r], red[64 + r]), fmaxf(red[128 + r], red[192 + r]));
        float nm = fmaxf(m_run, tm);
        float alpha = __expf(m_run - nm);             // 0 on first tile (-inf)

        float ls = 0.f;
        #pragma unroll
        for (int jj = 0; jj < 16; ++jj) {
            float p = __expf(sv[jj] - nm);
            ls += p;
            Ss[r * 68 + jb + jj] = p;
        }
        red[256 + t] = ls;
        __syncthreads();
        float tsum = (red[256 + r] + red[256 + 64 + r]) + (red[256 + 128 + r] + red[256 + 192 + r]);
        l_run = l_run * alpha + tsum;
        m_run = nm;

        #pragma unroll
        for (int cc = 0; cc < 16; ++cc) O[cc] *= alpha;

        // ----- O += P . V^T  (V via scalar loads, 16-wide contiguous) -----
        #pragma unroll
        for (int j16 = 0; j16 < 4; ++j16) {
            float p16[16];
            const float4* Sr = (const float4*)(Ss + r * 68 + j16 * 16);
            #pragma unroll
            for (int u = 0; u < 4; ++u) {
                float4 pv = Sr[u];
                p16[4 * u + 0] = pv.x; p16[4 * u + 1] = pv.y;
                p16[4 * u + 2] = pv.z; p16[4 * u + 3] = pv.w;
            }
            #pragma unroll
            for (int cc = 0; cc < 16; ++cc) {
                const float* vr = Vb + (cb + cc) * L + kt + j16 * 16;  // wave-uniform
                #pragma unroll
                for (int u = 0; u < 16; ++u) O[cc] += p16[u] * vr[u];
            }
        }
    }

    if (NSPLIT == 1) {
        float inv_l = 1.0f / l_run;
        if (resid != nullptr) {
            float gm = gamma_p[0];
            #pragma unroll
            for (int cc = 0; cc < 16; ++cc) {
                int oidx = (b * 64 + cb + cc) * NQ + m0 + r;
                Ofinal[oidx] = gm * (O[cc] * inv_l) + resid[oidx];
            }
        } else {
            #pragma unroll
            for (int cc = 0; cc < 16; ++cc) {
                int oidx = (b * 64 + cb + cc) * NQ + m0 + r;
                Ofinal[oidx] = O[cc] * inv_l;
            }
        }
    } else {
        #pragma unroll
        for (int cc = 0; cc < 16; ++cc)
            Opart[((b * NSPLIT + s) * 64 + cb + cc) * NQ + m0 + r] = O[cc];
        if (t < 64) {   // one writer per row (all 4 waves hold identical m/l)
            Mbuf[(b * NSPLIT + s) * NQ + m0 + r] = m_run;
            Lbuf[(b * NSPLIT + s) * NQ + m0 + r] = l_run;
        }
    }
}

// ---------------------------------------------------------------------------
// Combine NSPLIT=4 flash partials -> out1 (B,64,1024).
// ---------------------------------------------------------------------------
__global__ __launch_bounds__(256) void combine_kernel(
    const float* __restrict__ Opart, const float* __restrict__ Mbuf,
    const float* __restrict__ Lbuf, float* __restrict__ out1)
{
    int idx = blockIdx.x * 256 + threadIdx.x;   // over B*64*1024
    int m = idx & 1023;
    int c = (idx >> 10) & 63;
    int b = idx >> 16;

    float ms[4], ls[4];
    #pragma unroll
    for (int s = 0; s < 4; ++s) {
        ms[s] = Mbuf[(b * 4 + s) * 1024 + m];
        ls[s] = Lbuf[(b * 4 + s) * 1024 + m];
    }
    float M = fmaxf(fmaxf(ms[0], ms[1]), fmaxf(ms[2], ms[3]));
    float w[4], lt = 0.f;
    #pragma unroll
    for (int s = 0; s < 4; ++s) { w[s] = __expf(ms[s] - M); lt += ls[s] * w[s]; }
    float acc = 0.f;
    #pragma unroll
    for (int s = 0; s < 4; ++s)
        acc += Opart[((b * 4 + s) * 64 + c) * 1024 + m] * w[s];
    out1[(b * 64 + c) * 1024 + m] = acc / lt;
}

// ---------------------------------------------------------------------------
extern "C" void kernel_launch(void* const* d_in, const int* in_sizes, int n_in,
                              void* d_out, int out_size, void* d_ws, size_t ws_size,
                              hipStream_t stream) {
    const float* x    = (const float*)d_in[0];
    const float* w_q  = (const float*)d_in[1];
    const float* b_q  = (const float*)d_in[2];
    const float* w_K  = (const float*)d_in[3];
    const float* b_K  = (const float*)d_in[4];
    const float* w_V  = (const float*)d_in[5];
    const float* b_V  = (const float*)d_in[6];
    const float* w_Q  = (const float*)d_in[7];
    const float* b_Q  = (const float*)d_in[8];
    const float* w_k  = (const float*)d_in[9];
    const float* b_k  = (const float*)d_in[10];
    const float* w_v  = (const float*)d_in[11];
    const float* b_v  = (const float*)d_in[12];
    const float* gamma = (const float*)d_in[13];
    float* out = (float*)d_out;

    // Workspace layout (floats). Total ~11.08M floats = 44.3 MB.
    float* ws    = (float*)d_ws;
    float* Kf    = ws;                    // 8*64*4096 = 2097152
    float* Vf    = Kf    + 2097152;
    float* Qf    = Vf    + 2097152;
    float* xp    = Qf    + 2097152;       // 524288
    float* qp    = xp    + 524288;
    float* out1  = qp    + 524288;
    float* kp    = out1  + 524288;
    float* vp    = kp    + 524288;
    float* Opart = vp    + 524288;        // 8*4*64*1024 = 2097152
    float* Mb    = Opart + 2097152;       // 32768
    float* Lb    = Mb    + 32768;         // 32768

    // 1) pool x -> xp
    pool_kernel<<<2048, 256, 0, stream>>>(x, xp);

    // 2) K,V,Q projections of x (N=4096)
    proj_kernel<3><<<dim3(32, 8), 128, 0, stream>>>(
        x, 4096, w_K, b_K, Kf, w_V, b_V, Vf, w_Q, b_Q, Qf);

    // 3) pooled-query projection of xp (N=1024)
    proj_kernel<1><<<dim3(8, 8), 128, 0, stream>>>(
        xp, 1024, w_q, b_q, qp,
        nullptr, nullptr, nullptr, nullptr, nullptr, nullptr);

    // 4) stage-1 flash: qp (1024 rows) vs Kf/Vf (L=4096), split KV x4
    flash_kernel<4><<<dim3(16, 8, 4), 256, 0, stream>>>(
        qp, Kf, Vf, 1024, 4096,
        nullptr, nullptr, nullptr, Opart, Mb, Lb);

    // 5) combine partials -> out1 (B,64,1024)
    combine_kernel<<<2048, 256, 0, stream>>>(Opart, Mb, Lb, out1);

    // 6) k,v projections of out1 (N=1024)
    proj_kernel<2><<<dim3(8, 8), 128, 0, stream>>>(
        out1, 1024, w_k, b_k, kp, w_v, b_v, vp, nullptr, nullptr, nullptr);

    // 7) stage-2 flash: Qf (4096 rows) vs kp/vp (L=1024), epilogue gamma*O+x
    flash_kernel<1><<<dim3(64, 8, 1), 256, 0, stream>>>(
        Qf, kp, vp, 4096, 1024,
        out, x, gamma, nullptr, nullptr, nullptr);
}

// Round 2
// 481.342 us; speedup vs baseline: 2.8307x; 2.8307x over previous
//
#include <hip/hip_runtime.h>
#include <math.h>

// B=8, C=64, H=W=64, N=4096, N4=1024.
// bf16 MFMA flash attention; fp32 accumulate everywhere.

typedef __bf16 bf16;
typedef __attribute__((ext_vector_type(8))) __bf16 bf16x8;
typedef __attribute__((ext_vector_type(4))) float f32x4;

// ---------------------------------------------------------------------------
// 2x2 average pool: x (B,64,64,64) fp32 -> xp (B,64,32,32) fp32.
// ---------------------------------------------------------------------------
__global__ __launch_bounds__(256) void pool_kernel(const float* __restrict__ x,
                                                   float* __restrict__ xp) {
    int idx = blockIdx.x * 256 + threadIdx.x;   // B*64*1024
    int m  = idx & 1023;
    int hp = m >> 5, wp = m & 31;
    int bc = idx >> 10;
    const float* xb = x + bc * 4096 + hp * 128 + wp * 2;
    xp[idx] = 0.25f * (xb[0] + xb[1] + xb[64] + xb[65]);
}

// ---------------------------------------------------------------------------
// Projections from x (N=4096): z=0 -> Kt transposed (b,n,64) bf16,
// z=1 -> Qt transposed, z=2 -> V normal (b,64,n) bf16.
// ---------------------------------------------------------------------------
__global__ __launch_bounds__(64) void projx_kernel(
    const float* __restrict__ X,
    const float* __restrict__ W0, const float* __restrict__ B0, bf16* __restrict__ Kt,
    const float* __restrict__ W1, const float* __restrict__ B1, bf16* __restrict__ Qt,
    const float* __restrict__ W2, const float* __restrict__ B2, bf16* __restrict__ Vn)
{
    const int n = blockIdx.x * 64 + threadIdx.x;
    const int b = blockIdx.y;
    const int z = blockIdx.z;
    const float* W  = (z == 0) ? W0 : (z == 1) ? W1 : W2;
    const float* Bs = (z == 0) ? B0 : (z == 1) ? B1 : B2;

    float xv[64];
    #pragma unroll
    for (int c = 0; c < 64; ++c) xv[c] = X[(b * 64 + c) * 4096 + n];

    if (z < 2) {
        bf16* Y = (z == 0) ? Kt : Qt;
        alignas(16) bf16 yb[64];
        #pragma unroll 4
        for (int o = 0; o < 64; ++o) {
            float a = Bs[o];
            #pragma unroll
            for (int c = 0; c < 64; ++c) a += W[o * 64 + c] * xv[c];
            yb[o] = (bf16)a;
        }
        bf16x8* dst = (bf16x8*)(Y + ((size_t)b * 4096 + n) * 64);
        #pragma unroll
        for (int i = 0; i < 8; ++i) dst[i] = ((bf16x8*)yb)[i];
    } else {
        #pragma unroll 4
        for (int o = 0; o < 64; ++o) {
            float a = Bs[o];
            #pragma unroll
            for (int c = 0; c < 64; ++c) a += W[o * 64 + c] * xv[c];
            Vn[(b * 64 + o) * 4096 + n] = (bf16)a;
        }
    }
}

// ---------------------------------------------------------------------------
// Generic projection, N columns: z=0 -> Y0 transposed (b,n,64); z=1 -> Y1
// normal (b,64,n). Launch with gridDim.z = 1 or 2.
// ---------------------------------------------------------------------------
template<int N>
__global__ __launch_bounds__(64) void proj2_kernel(
    const float* __restrict__ X,
    const float* __restrict__ W0, const float* __restrict__ B0, bf16* __restrict__ Y0,
    const float* __restrict__ W1, const float* __restrict__ B1, bf16* __restrict__ Y1)
{
    const int n = blockIdx.x * 64 + threadIdx.x;
    const int b = blockIdx.y;
    const int z = blockIdx.z;
    const float* W  = (z == 0) ? W0 : W1;
    const float* Bs = (z == 0) ? B0 : B1;

    float xv[64];
    #pragma unroll
    for (int c = 0; c < 64; ++c) xv[c] = X[(b * 64 + c) * N + n];

    if (z == 0) {
        alignas(16) bf16 yb[64];
        #pragma unroll 4
        for (int o = 0; o < 64; ++o) {
            float a = Bs[o];
            #pragma unroll
            for (int c = 0; c < 64; ++c) a += W[o * 64 + c] * xv[c];
            yb[o] = (bf16)a;
        }
        bf16x8* dst = (bf16x8*)(Y0 + ((size_t)b * N + n) * 64);
        #pragma unroll
        for (int i = 0; i < 8; ++i) dst[i] = ((bf16x8*)yb)[i];
    } else {
        #pragma unroll 4
        for (int o = 0; o < 64; ++o) {
            float a = Bs[o];
            #pragma unroll
            for (int c = 0; c < 64; ++c) a += W[o * 64 + c] * xv[c];
            Y1[(b * 64 + o) * N + n] = (bf16)a;
        }
    }
}

// ---------------------------------------------------------------------------
// MFMA flash attention. 1 wave per block, 16 query rows, KV tiles of 64.
//   Qt: (B,NQ,64) bf16 transposed.  Kt: (B,L,64) bf16 transposed.
//   Vn: (B,64,L) bf16 original layout.
// S-tile: 4 m-tiles x 2 c-steps of mfma_f32_16x16x32_bf16 (frags from global).
// Softmax in-register (C-layout rows n = q4*4+reg, cols = lane&15).
// P -> LDS (bf16) -> A-frags; PV: 4 c-groups x 2 m-steps.
// NSPLIT>1: unnormalized partials + m,l. NSPLIT==1: gamma*O/l + resid.
// ---------------------------------------------------------------------------
template<int NSPLIT>
__global__ __launch_bounds__(64) void flash_mfma_kernel(
    const bf16* __restrict__ Qt, const bf16* __restrict__ Kt,
    const bf16* __restrict__ Vn, int NQ, int L,
    float* __restrict__ Ofinal, const float* __restrict__ resid,
    const float* __restrict__ gamma_p,
    float* __restrict__ Opart,   // (B, NSPLIT, 64, NQ)
    float* __restrict__ Mbuf,    // (B, NSPLIT, NQ)
    float* __restrict__ Lbuf)    // (B, NSPLIT, NQ)
{
    const int lane = threadIdx.x;        // 0..63
    const int c16  = lane & 15;
    const int q4   = lane >> 4;          // 0..3
    const int b    = blockIdx.y;
    const int n0   = blockIdx.x * 16;
    const int s    = (NSPLIT > 1) ? blockIdx.z : 0;
    const int SL   = L / NSPLIT;
    const int k0   = s * SL, k1 = k0 + SL;

    __shared__ __align__(16) bf16 Ps[16 * 72];   // P tile (16 n x 64 m, stride 72)
    __shared__ float Os[64 * 17];                // epilogue transpose

    // Q A-frags (row n = n0 + c16, channels q4*8.. and +32)
    const bf16* qrow = Qt + ((size_t)b * NQ + n0 + c16) * 64 + q4 * 8;
    bf16x8 aq0 = *(const bf16x8*)(qrow);
    bf16x8 aq1 = *(const bf16x8*)(qrow + 32);

    f32x4 O[4];
    #pragma unroll
    for (int g = 0; g < 4; ++g) O[g] = (f32x4){0.f, 0.f, 0.f, 0.f};
    float m_run[4], l_run[4];
    #pragma unroll
    for (int r = 0; r < 4; ++r) { m_run[r] = -INFINITY; l_run[r] = 0.f; }

    const bf16* Kb = Kt + (size_t)b * L * 64;
    const bf16* Vb = Vn + (size_t)b * 64 * L;

    for (int kt = k0; kt < k1; kt += 64) {
        // ---- S = Q.K^T for 16 n x 64 m ----
        f32x4 sv[4];
        #pragma unroll
        for (int t = 0; t < 4; ++t) {
            const bf16* krow = Kb + ((size_t)(kt + 16 * t + c16)) * 64 + q4 * 8;
            bf16x8 bk0 = *(const bf16x8*)(krow);
            bf16x8 bk1 = *(const bf16x8*)(krow + 32);
            f32x4 z = (f32x4){0.f, 0.f, 0.f, 0.f};
            z = __builtin_amdgcn_mfma_f32_16x16x32_bf16(aq0, bk0, z, 0, 0, 0);
            sv[t] = __builtin_amdgcn_mfma_f32_16x16x32_bf16(aq1, bk1, z, 0, 0, 0);
        }

        // ---- row stats (rows n = q4*4 + r) ----
        float tm[4];
        #pragma unroll
        for (int r = 0; r < 4; ++r)
            tm[r] = fmaxf(fmaxf(sv[0][r], sv[1][r]), fmaxf(sv[2][r], sv[3][r]));
        #pragma unroll
        for (int off = 1; off < 16; off <<= 1) {
            #pragma unroll
            for (int r = 0; r < 4; ++r) tm[r] = fmaxf(tm[r], __shfl_xor(tm[r], off));
        }
        float alpha[4];
        #pragma unroll
        for (int r = 0; r < 4; ++r) {
            float nm = fmaxf(m_run[r], tm[r]);
            alpha[r] = __expf(m_run[r] - nm);
            m_run[r] = nm;
        }
        float ls[4] = {0.f, 0.f, 0.f, 0.f};
        #pragma unroll
        for (int t = 0; t < 4; ++t) {
            #pragma unroll
            for (int r = 0; r < 4; ++r) {
                float p = __expf(sv[t][r] - m_run[r]);
                sv[t][r] = p;
                ls[r] += p;
            }
        }
        #pragma unroll
        for (int off = 1; off < 16; off <<= 1) {
            #pragma unroll
            for (int r = 0; r < 4; ++r) ls[r] += __shfl_xor(ls[r], off);
        }
        #pragma unroll
        for (int r = 0; r < 4; ++r) l_run[r] = l_run[r] * alpha[r] + ls[r];
        #pragma unroll
        for (int g = 0; g < 4; ++g) {
            #pragma unroll
            for (int r = 0; r < 4; ++r) O[g][r] *= alpha[r];
        }

        // ---- P (bf16) to LDS in (n, m) m-contiguous layout ----
        #pragma unroll
        for (int t = 0; t < 4; ++t) {
            #pragma unroll
            for (int r = 0; r < 4; ++r)
                Ps[(q4 * 4 + r) * 72 + 16 * t + c16] = (bf16)sv[t][r];
        }
        __syncthreads();

        // ---- P A-frags ----
        const bf16* prow = Ps + c16 * 72 + q4 * 8;
        bf16x8 pa0 = *(const bf16x8*)(prow);
        bf16x8 pa1 = *(const bf16x8*)(prow + 32);

        // ---- O += P.V^T ----
        #pragma unroll
        for (int g = 0; g < 4; ++g) {
            const bf16* vrow = Vb + ((size_t)(16 * g + c16)) * L + kt + q4 * 8;
            bf16x8 bv0 = *(const bf16x8*)(vrow);
            bf16x8 bv1 = *(const bf16x8*)(vrow + 32);
            O[g] = __builtin_amdgcn_mfma_f32_16x16x32_bf16(pa0, bv0, O[g], 0, 0, 0);
            O[g] = __builtin_amdgcn_mfma_f32_16x16x32_bf16(pa1, bv1, O[g], 0, 0, 0);
        }
        __syncthreads();   // protect Ps before next tile's writes
    }

    if (NSPLIT == 1) {
        float gm = gamma_p[0];
        float inv[4];
        #pragma unroll
        for (int r = 0; r < 4; ++r) inv[r] = gm / l_run[r];
        #pragma unroll
        for (int g = 0; g < 4; ++g) {
            #pragma unroll
            for (int r = 0; r < 4; ++r)
                Os[(16 * g + c16) * 17 + q4 * 4 + r] = O[g][r] * inv[r];
        }
        __syncthreads();
        #pragma unroll
        for (int i = 0; i < 16; ++i) {
            int idx = i * 64 + lane;
            int c = idx >> 4, nl = idx & 15;
            int oidx = (b * 64 + c) * NQ + n0 + nl;
            Ofinal[oidx] = Os[c * 17 + nl] + resid[oidx];
        }
    } else {
        #pragma unroll
        for (int g = 0; g < 4; ++g) {
            #pragma unroll
            for (int r = 0; r < 4; ++r)
                Os[(16 * g + c16) * 17 + q4 * 4 + r] = O[g][r];
        }
        __syncthreads();
        #pragma unroll
        for (int i = 0; i < 16; ++i) {
            int idx = i * 64 + lane;
            int c = idx >> 4, nl = idx & 15;
            Opart[((size_t)(b * NSPLIT + s) * 64 + c) * NQ + n0 + nl] = Os[c * 17 + nl];
        }
        if (c16 == 0) {
            #pragma unroll
            for (int r = 0; r < 4; ++r) {
                Mbuf[(b * NSPLIT + s) * NQ + n0 + q4 * 4 + r] = m_run[r];
                Lbuf[(b * NSPLIT + s) * NQ + n0 + q4 * 4 + r] = l_run[r];
            }
        }
    }
}

// ---------------------------------------------------------------------------
// Combine NSPLIT=4 partials -> out1 (B,64,1024) fp32.
// ---------------------------------------------------------------------------
__global__ __launch_bounds__(256) void combine_kernel(
    const float* __restrict__ Opart, const float* __restrict__ Mbuf,
    const float* __restrict__ Lbuf, float* __restrict__ out1)
{
    int idx = blockIdx.x * 256 + threadIdx.x;   // B*64*1024
    int m = idx & 1023;
    int c = (idx >> 10) & 63;
    int b = idx >> 16;

    float ms[4], ls[4];
    #pragma unroll
    for (int s = 0; s < 4; ++s) {
        ms[s] = Mbuf[(b * 4 + s) * 1024 + m];
        ls[s] = Lbuf[(b * 4 + s) * 1024 + m];
    }
    float M = fmaxf(fmaxf(ms[0], ms[1]), fmaxf(ms[2], ms[3]));
    float w[4], lt = 0.f;
    #pragma unroll
    for (int s = 0; s < 4; ++s) { w[s] = __expf(ms[s] - M); lt += ls[s] * w[s]; }
    float acc = 0.f;
    #pragma unroll
    for (int s = 0; s < 4; ++s)
        acc += Opart[((size_t)(b * 4 + s) * 64 + c) * 1024 + m] * w[s];
    out1[(b * 64 + c) * 1024 + m] = acc / lt;
}

// ---------------------------------------------------------------------------
extern "C" void kernel_launch(void* const* d_in, const int* in_sizes, int n_in,
                              void* d_out, int out_size, void* d_ws, size_t ws_size,
                              hipStream_t stream) {
    const float* x    = (const float*)d_in[0];
    const float* w_q  = (const float*)d_in[1];
    const float* b_q  = (const float*)d_in[2];
    const float* w_K  = (const float*)d_in[3];
    const float* b_K  = (const float*)d_in[4];
    const float* w_V  = (const float*)d_in[5];
    const float* b_V  = (const float*)d_in[6];
    const float* w_Q  = (const float*)d_in[7];
    const float* b_Q  = (const float*)d_in[8];
    const float* w_k  = (const float*)d_in[9];
    const float* b_k  = (const float*)d_in[10];
    const float* w_v  = (const float*)d_in[11];
    const float* b_v  = (const float*)d_in[12];
    const float* gamma = (const float*)d_in[13];
    float* out = (float*)d_out;

    // Workspace layout (bytes):
    char* ws = (char*)d_ws;
    bf16*  Kt    = (bf16*)ws;                      ws += (size_t)8 * 4096 * 64 * 2;  // 4MB
    bf16*  Qt    = (bf16*)ws;                      ws += (size_t)8 * 4096 * 64 * 2;  // 4MB
    bf16*  Vf    = (bf16*)ws;                      ws += (size_t)8 * 4096 * 64 * 2;  // 4MB
    float* xp    = (float*)ws;                     ws += (size_t)8 * 64 * 1024 * 4;  // 2MB
    bf16*  qpt   = (bf16*)ws;                      ws += (size_t)8 * 1024 * 64 * 2;  // 1MB
    float* out1  = (float*)ws;                     ws += (size_t)8 * 64 * 1024 * 4;  // 2MB
    bf16*  kpt   = (bf16*)ws;                      ws += (size_t)8 * 1024 * 64 * 2;  // 1MB
    bf16*  vp    = (bf16*)ws;                      ws += (size_t)8 * 64 * 1024 * 2;  // 1MB
    float* Opart = (float*)ws;                     ws += (size_t)8 * 4 * 64 * 1024 * 4; // 8MB
    float* Mb    = (float*)ws;                     ws += (size_t)8 * 4 * 1024 * 4;   // 128KB
    float* Lb    = (float*)ws;                     ws += (size_t)8 * 4 * 1024 * 4;   // 128KB

    // 1) pool x -> xp (fp32)
    pool_kernel<<<2048, 256, 0, stream>>>(x, xp);

    // 2) K,Q (transposed bf16) and V (normal bf16) projections of x
    projx_kernel<<<dim3(64, 8, 3), 64, 0, stream>>>(
        x, w_K, b_K, Kt, w_Q, b_Q, Qt, w_V, b_V, Vf);

    // 3) pooled-query projection (transposed bf16)
    proj2_kernel<1024><<<dim3(16, 8, 1), 64, 0, stream>>>(
        xp, w_q, b_q, qpt, nullptr, nullptr, nullptr);

    // 4) stage-1 flash: qpt (1024 q) vs Kt/Vf (L=4096), split x4
    flash_mfma_kernel<4><<<dim3(64, 8, 4), 64, 0, stream>>>(
        qpt, Kt, Vf, 1024, 4096,
        nullptr, nullptr, nullptr, Opart, Mb, Lb);

    // 5) combine -> out1 (B,64,1024) fp32
    combine_kernel<<<2048, 256, 0, stream>>>(Opart, Mb, Lb, out1);

    // 6) k (transposed) and v (normal) projections of out1
    proj2_kernel<1024><<<dim3(16, 8, 2), 64, 0, stream>>>(
        out1, w_k, b_k, kpt, w_v, b_v, vp);

    // 7) stage-2 flash: Qt (4096 q) vs kpt/vp (L=1024), epilogue gamma*O/l + x
    flash_mfma_kernel<1><<<dim3(256, 8, 1), 64, 0, stream>>>(
        Qt, kpt, vp, 4096, 1024,
        out, x, gamma, nullptr, nullptr, nullptr);
}

// Round 3
// 246.353 us; speedup vs baseline: 5.5308x; 1.9539x over previous
//
#include <hip/hip_runtime.h>
#include <math.h>

// B=8, C=64, H=W=64, N=4096, N4=1024. bf16 MFMA everywhere, fp32 accumulate.

typedef __bf16 bf16;
typedef __attribute__((ext_vector_type(4))) __bf16 bf16x4;
typedef __attribute__((ext_vector_type(8))) __bf16 bf16x8;
typedef __attribute__((ext_vector_type(4))) float f32x4;

// ---------------------------------------------------------------------------
// Transpose-cast: x (B,64,4096) fp32 -> xT (B,4096,64) bf16. LDS 64x64 tile.
// ---------------------------------------------------------------------------
__global__ __launch_bounds__(256) void transpose_kernel(const float* __restrict__ x,
                                                        bf16* __restrict__ xT) {
    __shared__ float tile[64 * 65];
    const int t  = threadIdx.x;
    const int n0 = blockIdx.x * 64;
    const int b  = blockIdx.y;
    #pragma unroll
    for (int i = 0; i < 16; ++i) {
        int lin = i * 256 + t;
        int n = lin & 63, c = lin >> 6;
        tile[n * 65 + c] = x[((size_t)b * 64 + c) * 4096 + n0 + n];
    }
    __syncthreads();
    #pragma unroll
    for (int i = 0; i < 2; ++i) {
        int slot = i * 256 + t;
        int n = slot >> 3, c0 = (slot & 7) * 8;
        bf16 tmp[8];
        #pragma unroll
        for (int j = 0; j < 8; ++j) tmp[j] = (bf16)tile[n * 65 + c0 + j];
        *(bf16x8*)(xT + ((size_t)b * 4096 + n0 + n) * 64 + c0) = *(bf16x8*)tmp;
    }
}

// ---------------------------------------------------------------------------
// 2x2 avg pool on transposed layout: xT (B,4096,64) -> xpT (B,1024,64) bf16.
// ---------------------------------------------------------------------------
__global__ __launch_bounds__(256) void poolT_kernel(const bf16* __restrict__ xT,
                                                    bf16* __restrict__ xpT) {
    int slot = blockIdx.x * 256 + threadIdx.x;   // 8*1024*8 octets
    int c0 = (slot & 7) * 8;
    int m  = (slot >> 3) & 1023;
    int b  = slot >> 13;
    int hp = m >> 5, wp = m & 31;
    int n00 = (hp * 2) * 64 + wp * 2;
    const bf16* base = xT + ((size_t)b * 4096) * 64;
    float acc[8] = {0, 0, 0, 0, 0, 0, 0, 0};
    const int offs[4] = {n00, n00 + 1, n00 + 64, n00 + 65};
    #pragma unroll
    for (int u = 0; u < 4; ++u) {
        bf16x8 v = *(const bf16x8*)(base + (size_t)offs[u] * 64 + c0);
        #pragma unroll
        for (int j = 0; j < 8; ++j) acc[j] += (float)v[j];
    }
    bf16 outv[8];
    #pragma unroll
    for (int j = 0; j < 8; ++j) outv[j] = (bf16)(0.25f * acc[j]);
    *(bf16x8*)(xpT + ((size_t)b * 1024 + m) * 64 + c0) = *(bf16x8*)outv;
}

// ---------------------------------------------------------------------------
// MFMA 1x1-conv: one wave computes a full 64 o x 64 n tile (32 MFMAs).
//   XT: (B,N,64) bf16 channel-contiguous.  W,bias fp32.
//   tr=1 -> Y transposed (B,N,64); tr=0 -> Y normal (B,64,N).
// grid = (N/64, B, nz); blockIdx.z selects the weight set.
// ---------------------------------------------------------------------------
__global__ __launch_bounds__(64) void proj_mfma_kernel(
    const bf16* __restrict__ XT, int N,
    const float* __restrict__ W0, const float* __restrict__ B0, bf16* __restrict__ Y0, int t0,
    const float* __restrict__ W1, const float* __restrict__ B1, bf16* __restrict__ Y1, int t1,
    const float* __restrict__ W2, const float* __restrict__ B2, bf16* __restrict__ Y2, int t2)
{
    const int lane = threadIdx.x;
    const int c16 = lane & 15, q4 = lane >> 4;
    const int n0 = blockIdx.x * 64;
    const int b  = blockIdx.y;
    const int z  = blockIdx.z;
    const float* W  = (z == 0) ? W0 : (z == 1) ? W1 : W2;
    const float* Bs = (z == 0) ? B0 : (z == 1) ? B1 : B2;
    bf16*        Y  = (z == 0) ? Y0 : (z == 1) ? Y1 : Y2;
    const int    tr = (z == 0) ? t0 : (z == 1) ? t1 : t2;

    // A-frags: W[o = 16to + c16][k = q4*8 + 32h + j]
    bf16x8 wa[4][2];
    #pragma unroll
    for (int to = 0; to < 4; ++to)
        #pragma unroll
        for (int h = 0; h < 2; ++h) {
            const float* wp = W + (16 * to + c16) * 64 + q4 * 8 + 32 * h;
            float4 f0 = *(const float4*)wp;
            float4 f1 = *(const float4*)(wp + 4);
            bf16 tmp[8] = {(bf16)f0.x, (bf16)f0.y, (bf16)f0.z, (bf16)f0.w,
                           (bf16)f1.x, (bf16)f1.y, (bf16)f1.z, (bf16)f1.w};
            wa[to][h] = *(bf16x8*)tmp;
        }

    f32x4 acc[4][4];
    #pragma unroll
    for (int to = 0; to < 4; ++to)
        #pragma unroll
        for (int tn = 0; tn < 4; ++tn) acc[to][tn] = (f32x4){0.f, 0.f, 0.f, 0.f};

    #pragma unroll
    for (int tn = 0; tn < 4; ++tn) {
        const bf16* xrow = XT + ((size_t)b * N + n0 + 16 * tn + c16) * 64 + q4 * 8;
        bf16x8 xb0 = *(const bf16x8*)xrow;
        bf16x8 xb1 = *(const bf16x8*)(xrow + 32);
        #pragma unroll
        for (int to = 0; to < 4; ++to) {
            acc[to][tn] = __builtin_amdgcn_mfma_f32_16x16x32_bf16(wa[to][0], xb0, acc[to][tn], 0, 0, 0);
            acc[to][tn] = __builtin_amdgcn_mfma_f32_16x16x32_bf16(wa[to][1], xb1, acc[to][tn], 0, 0, 0);
        }
    }

    #pragma unroll
    for (int to = 0; to < 4; ++to) {
        float4 b4 = *(const float4*)(Bs + 16 * to + q4 * 4);
        float bias[4] = {b4.x, b4.y, b4.z, b4.w};
        #pragma unroll
        for (int tn = 0; tn < 4; ++tn) {
            if (tr) {
                bf16 yv[4];
                #pragma unroll
                for (int r = 0; r < 4; ++r) yv[r] = (bf16)(acc[to][tn][r] + bias[r]);
                *(bf16x4*)(Y + ((size_t)b * N + n0 + 16 * tn + c16) * 64 + 16 * to + q4 * 4) = *(bf16x4*)yv;
            } else {
                #pragma unroll
                for (int r = 0; r < 4; ++r)
                    Y[((size_t)b * 64 + 16 * to + q4 * 4 + r) * N + n0 + 16 * tn + c16] =
                        (bf16)(acc[to][tn][r] + bias[r]);
            }
        }
    }
}

// ---------------------------------------------------------------------------
// MFMA flash attention. 1 wave/block, 16 queries, KV tiles of 64.
//   Qt: (B,NQ,64), Kt: (B,L,64) bf16 transposed; Vn: (B,64,L) bf16.
// Always writes unnormalized partials + m,l (split-KV).
//   PLAYOUT=0: Opart (B,NSPLIT,64,NQ) channel-major (stage 2)
//   PLAYOUT=1: Opart (B,NSPLIT,NQ,64) row-major     (stage 1)
// ---------------------------------------------------------------------------
template<int NSPLIT, int PLAYOUT>
__global__ __launch_bounds__(64) void flash_mfma_kernel(
    const bf16* __restrict__ Qt, const bf16* __restrict__ Kt,
    const bf16* __restrict__ Vn, int NQ, int L,
    float* __restrict__ Opart, float* __restrict__ Mbuf, float* __restrict__ Lbuf)
{
    const int lane = threadIdx.x;
    const int c16  = lane & 15;
    const int q4   = lane >> 4;
    const int b    = blockIdx.y;
    const int n0   = blockIdx.x * 16;
    const int s    = blockIdx.z;
    const int SL   = L / NSPLIT;
    const int k0   = s * SL, k1 = k0 + SL;

    __shared__ __align__(16) bf16 Ps[16 * 72];
    __shared__ float Os[64 * 17];

    const bf16* qrow = Qt + ((size_t)b * NQ + n0 + c16) * 64 + q4 * 8;
    bf16x8 aq0 = *(const bf16x8*)(qrow);
    bf16x8 aq1 = *(const bf16x8*)(qrow + 32);

    f32x4 O[4];
    #pragma unroll
    for (int g = 0; g < 4; ++g) O[g] = (f32x4){0.f, 0.f, 0.f, 0.f};
    float m_run[4], l_run[4];
    #pragma unroll
    for (int r = 0; r < 4; ++r) { m_run[r] = -INFINITY; l_run[r] = 0.f; }

    const bf16* Kb = Kt + (size_t)b * L * 64;
    const bf16* Vb = Vn + (size_t)b * 64 * L;

    for (int kt = k0; kt < k1; kt += 64) {
        f32x4 sv[4];
        #pragma unroll
        for (int t = 0; t < 4; ++t) {
            const bf16* krow = Kb + ((size_t)(kt + 16 * t + c16)) * 64 + q4 * 8;
            bf16x8 bk0 = *(const bf16x8*)(krow);
            bf16x8 bk1 = *(const bf16x8*)(krow + 32);
            f32x4 z = (f32x4){0.f, 0.f, 0.f, 0.f};
            z = __builtin_amdgcn_mfma_f32_16x16x32_bf16(aq0, bk0, z, 0, 0, 0);
            sv[t] = __builtin_amdgcn_mfma_f32_16x16x32_bf16(aq1, bk1, z, 0, 0, 0);
        }

        float tm[4];
        #pragma unroll
        for (int r = 0; r < 4; ++r)
            tm[r] = fmaxf(fmaxf(sv[0][r], sv[1][r]), fmaxf(sv[2][r], sv[3][r]));
        #pragma unroll
        for (int off = 1; off < 16; off <<= 1) {
            #pragma unroll
            for (int r = 0; r < 4; ++r) tm[r] = fmaxf(tm[r], __shfl_xor(tm[r], off));
        }
        float alpha[4];
        #pragma unroll
        for (int r = 0; r < 4; ++r) {
            float nm = fmaxf(m_run[r], tm[r]);
            alpha[r] = __expf(m_run[r] - nm);
            m_run[r] = nm;
        }
        float ls[4] = {0.f, 0.f, 0.f, 0.f};
        #pragma unroll
        for (int t = 0; t < 4; ++t) {
            #pragma unroll
            for (int r = 0; r < 4; ++r) {
                float p = __expf(sv[t][r] - m_run[r]);
                sv[t][r] = p;
                ls[r] += p;
            }
        }
        #pragma unroll
        for (int off = 1; off < 16; off <<= 1) {
            #pragma unroll
            for (int r = 0; r < 4; ++r) ls[r] += __shfl_xor(ls[r], off);
        }
        #pragma unroll
        for (int r = 0; r < 4; ++r) l_run[r] = l_run[r] * alpha[r] + ls[r];
        #pragma unroll
        for (int g = 0; g < 4; ++g) {
            #pragma unroll
            for (int r = 0; r < 4; ++r) O[g][r] *= alpha[r];
        }

        #pragma unroll
        for (int t = 0; t < 4; ++t) {
            #pragma unroll
            for (int r = 0; r < 4; ++r)
                Ps[(q4 * 4 + r) * 72 + 16 * t + c16] = (bf16)sv[t][r];
        }
        __syncthreads();

        const bf16* prow = Ps + c16 * 72 + q4 * 8;
        bf16x8 pa0 = *(const bf16x8*)(prow);
        bf16x8 pa1 = *(const bf16x8*)(prow + 32);

        #pragma unroll
        for (int g = 0; g < 4; ++g) {
            const bf16* vrow = Vb + ((size_t)(16 * g + c16)) * L + kt + q4 * 8;
            bf16x8 bv0 = *(const bf16x8*)(vrow);
            bf16x8 bv1 = *(const bf16x8*)(vrow + 32);
            O[g] = __builtin_amdgcn_mfma_f32_16x16x32_bf16(pa0, bv0, O[g], 0, 0, 0);
            O[g] = __builtin_amdgcn_mfma_f32_16x16x32_bf16(pa1, bv1, O[g], 0, 0, 0);
        }
        __syncthreads();
    }

    // epilogue: Os[channel][m-local], stride 17
    #pragma unroll
    for (int g = 0; g < 4; ++g) {
        #pragma unroll
        for (int r = 0; r < 4; ++r)
            Os[(16 * g + c16) * 17 + q4 * 4 + r] = O[g][r];
    }
    __syncthreads();
    if (PLAYOUT == 0) {
        #pragma unroll
        for (int i = 0; i < 16; ++i) {
            int idx = i * 64 + lane;
            int c = idx >> 4, nl = idx & 15;
            Opart[((size_t)(b * NSPLIT + s) * 64 + c) * NQ + n0 + nl] = Os[c * 17 + nl];
        }
    } else {
        #pragma unroll
        for (int i = 0; i < 16; ++i)
            Opart[((size_t)(b * NSPLIT + s) * NQ + n0 + i) * 64 + lane] = Os[lane * 17 + i];
    }
    if (c16 == 0) {
        #pragma unroll
        for (int r = 0; r < 4; ++r) {
            Mbuf[(b * NSPLIT + s) * NQ + n0 + q4 * 4 + r] = m_run[r];
            Lbuf[(b * NSPLIT + s) * NQ + n0 + q4 * 4 + r] = l_run[r];
        }
    }
}

// ---------------------------------------------------------------------------
// Combine stage-1 partials (8 splits, row-major) -> out1T (B,1024,64) bf16.
// ---------------------------------------------------------------------------
__global__ __launch_bounds__(256) void combine1_kernel(
    const float* __restrict__ Opart, const float* __restrict__ Mbuf,
    const float* __restrict__ Lbuf, bf16* __restrict__ out1T)
{
    int idx = blockIdx.x * 256 + threadIdx.x;   // 8*1024*64
    int c = idx & 63;
    int m = (idx >> 6) & 1023;
    int b = idx >> 16;
    float ms[8], ls[8];
    #pragma unroll
    for (int s = 0; s < 8; ++s) {
        ms[s] = Mbuf[(b * 8 + s) * 1024 + m];
        ls[s] = Lbuf[(b * 8 + s) * 1024 + m];
    }
    float M = ms[0];
    #pragma unroll
    for (int s = 1; s < 8; ++s) M = fmaxf(M, ms[s]);
    float lt = 0.f, acc = 0.f;
    #pragma unroll
    for (int s = 0; s < 8; ++s) {
        float w = __expf(ms[s] - M);
        lt += ls[s] * w;
        acc += Opart[((size_t)(b * 8 + s) * 1024 + m) * 64 + c] * w;
    }
    out1T[idx] = (bf16)(acc / lt);
}

// ---------------------------------------------------------------------------
// Combine stage-2 partials (2 splits, channel-major) + gamma*. + residual
// -> out (B,64,4096) fp32.
// ---------------------------------------------------------------------------
__global__ __launch_bounds__(256) void combine2_kernel(
    const float* __restrict__ Opart, const float* __restrict__ Mbuf,
    const float* __restrict__ Lbuf, const float* __restrict__ x,
    const float* __restrict__ gamma_p, float* __restrict__ out)
{
    int idx = blockIdx.x * 256 + threadIdx.x;   // 8*64*4096
    int n = idx & 4095;
    int b = idx >> 18;
    float m0 = Mbuf[(b * 2 + 0) * 4096 + n], m1 = Mbuf[(b * 2 + 1) * 4096 + n];
    float l0 = Lbuf[(b * 2 + 0) * 4096 + n], l1 = Lbuf[(b * 2 + 1) * 4096 + n];
    float M = fmaxf(m0, m1);
    float w0 = __expf(m0 - M), w1 = __expf(m1 - M);
    float lt = l0 * w0 + l1 * w1;
    int c = (idx >> 12) & 63;
    float acc = Opart[((size_t)(b * 2 + 0) * 64 + c) * 4096 + n] * w0
              + Opart[((size_t)(b * 2 + 1) * 64 + c) * 4096 + n] * w1;
    out[idx] = gamma_p[0] * (acc / lt) + x[idx];
}

// ---------------------------------------------------------------------------
extern "C" void kernel_launch(void* const* d_in, const int* in_sizes, int n_in,
                              void* d_out, int out_size, void* d_ws, size_t ws_size,
                              hipStream_t stream) {
    const float* x    = (const float*)d_in[0];
    const float* w_q  = (const float*)d_in[1];
    const float* b_q  = (const float*)d_in[2];
    const float* w_K  = (const float*)d_in[3];
    const float* b_K  = (const float*)d_in[4];
    const float* w_V  = (const float*)d_in[5];
    const float* b_V  = (const float*)d_in[6];
    const float* w_Q  = (const float*)d_in[7];
    const float* b_Q  = (const float*)d_in[8];
    const float* w_k  = (const float*)d_in[9];
    const float* b_k  = (const float*)d_in[10];
    const float* w_v  = (const float*)d_in[11];
    const float* b_v  = (const float*)d_in[12];
    const float* gamma = (const float*)d_in[13];
    float* out = (float*)d_out;

    char* ws = (char*)d_ws;
    bf16*  xT    = (bf16*)ws;   ws += (size_t)8 * 4096 * 64 * 2;       // 4MB
    bf16*  Kt    = (bf16*)ws;   ws += (size_t)8 * 4096 * 64 * 2;       // 4MB
    bf16*  Qt    = (bf16*)ws;   ws += (size_t)8 * 4096 * 64 * 2;       // 4MB
    bf16*  Vf    = (bf16*)ws;   ws += (size_t)8 * 4096 * 64 * 2;       // 4MB
    bf16*  xpT   = (bf16*)ws;   ws += (size_t)8 * 1024 * 64 * 2;       // 1MB
    bf16*  qpt   = (bf16*)ws;   ws += (size_t)8 * 1024 * 64 * 2;       // 1MB
    bf16*  out1T = (bf16*)ws;   ws += (size_t)8 * 1024 * 64 * 2;       // 1MB
    bf16*  kpt   = (bf16*)ws;   ws += (size_t)8 * 1024 * 64 * 2;       // 1MB
    bf16*  vp    = (bf16*)ws;   ws += (size_t)8 * 64 * 1024 * 2;       // 1MB
    float* Opart = (float*)ws;  ws += (size_t)8 * 8 * 1024 * 64 * 4;   // 16MB (shared by both stages)
    float* Mb    = (float*)ws;  ws += (size_t)8 * 8 * 1024 * 4;        // 256KB (shared)
    float* Lb    = (float*)ws;  ws += (size_t)8 * 8 * 1024 * 4;        // 256KB (shared)

    // 1) transpose-cast x -> xT
    transpose_kernel<<<dim3(64, 8), 256, 0, stream>>>(x, xT);

    // 2) pool xT -> xpT
    poolT_kernel<<<256, 256, 0, stream>>>(xT, xpT);

    // 3) K,Q (transposed) and V (normal) projections of xT
    proj_mfma_kernel<<<dim3(64, 8, 3), 64, 0, stream>>>(
        xT, 4096, w_K, b_K, Kt, 1, w_Q, b_Q, Qt, 1, w_V, b_V, Vf, 0);

    // 4) pooled-query projection (transposed)
    proj_mfma_kernel<<<dim3(16, 8, 1), 64, 0, stream>>>(
        xpT, 1024, w_q, b_q, qpt, 1,
        nullptr, nullptr, nullptr, 0, nullptr, nullptr, nullptr, 0);

    // 5) stage-1 flash: qpt (1024 q) vs Kt/Vf (L=4096), split x8, row-major partials
    flash_mfma_kernel<8, 1><<<dim3(64, 8, 8), 64, 0, stream>>>(
        qpt, Kt, Vf, 1024, 4096, Opart, Mb, Lb);

    // 6) combine -> out1T (B,1024,64) bf16
    combine1_kernel<<<2048, 256, 0, stream>>>(Opart, Mb, Lb, out1T);

    // 7) k (transposed) and v (normal) projections of out1T
    proj_mfma_kernel<<<dim3(16, 8, 2), 64, 0, stream>>>(
        out1T, 1024, w_k, b_k, kpt, 1, w_v, b_v, vp, 0,
        nullptr, nullptr, nullptr, 0);

    // 8) stage-2 flash: Qt (4096 q) vs kpt/vp (L=1024), split x2, channel-major partials
    flash_mfma_kernel<2, 0><<<dim3(256, 8, 2), 64, 0, stream>>>(
        Qt, kpt, vp, 4096, 1024, Opart, Mb, Lb);

    // 9) combine + gamma*. + residual -> out (B,64,4096) fp32
    combine2_kernel<<<8192, 256, 0, stream>>>(Opart, Mb, Lb, x, gamma, out);
}